// Round 1
// baseline (130.481 us; speedup 1.0000x reference)
//
#include <hip/hip_runtime.h>
#include <stdint.h>

#define NROWS 8192
#define DIM 128

typedef __bf16 bf16x8 __attribute__((ext_vector_type(8)));
typedef float floatx4 __attribute__((ext_vector_type(4)));

// ---------- helpers ----------
static __device__ __forceinline__ unsigned short f2bf(float f) {
    unsigned int u = __float_as_uint(f);
    unsigned int r = (u + 0x7FFFu + ((u >> 16) & 1u)) >> 16;   // RNE
    return (unsigned short)r;
}

// ---------- kernel 1: normalize rows, emit bf16 a_hat + pos_dist + init max keys ----------
__global__ __launch_bounds__(256) void normalize_kernel(
    const float* __restrict__ anchor, const float* __restrict__ positive,
    unsigned short* __restrict__ a_hat, float* __restrict__ pos_ws,
    int* __restrict__ g_ws)
{
    const int wave = threadIdx.x >> 6;
    const int lane = threadIdx.x & 63;
    const int row  = blockIdx.x * 4 + wave;

    const float2* arow = (const float2*)(anchor   + row * DIM);
    const float2* prow = (const float2*)(positive + row * DIM);
    float2 a = arow[lane];
    float2 p = prow[lane];

    float sa  = a.x * a.x + a.y * a.y;
    float sp  = p.x * p.x + p.y * p.y;
    float sap = a.x * p.x + a.y * p.y;
    #pragma unroll
    for (int off = 32; off; off >>= 1) {
        sa  += __shfl_xor(sa,  off);
        sp  += __shfl_xor(sp,  off);
        sap += __shfl_xor(sap, off);
    }
    float na  = fmaxf(sqrtf(sa), 1e-12f);
    float npn = fmaxf(sqrtf(sp), 1e-12f);
    float inv = 1.0f / na;

    ushort2 pack;
    pack.x = f2bf(a.x * inv);
    pack.y = f2bf(a.y * inv);
    ((ushort2*)a_hat)[row * 64 + lane] = pack;

    if (lane == 0) {
        pos_ws[row] = 2.0f - 2.0f * sap / (na * npn);
        g_ws[row]   = 0x3F800000;   // key for g = -1  (key = 2+g = 1.0f)
    }
}

// ---------- kernel 2: fused gram row-max with label mask ----------
// grid = 512: blockIdx>>3 = row block (128 rows), blockIdx&7 = 1024-col chunk.
// Each wave: 32-row strip, loops 32-col blocks, 2x2 tiles of 16x16x32 MFMA.
__global__ __launch_bounds__(256) void gram_kernel(
    const unsigned short* __restrict__ a_hat, const int* __restrict__ labels,
    int* __restrict__ g_ws)
{
    const int lane = threadIdx.x & 63;
    const int wave = threadIdx.x >> 6;
    const int quad = lane >> 4;
    const int l15  = lane & 15;

    const int rowBlock = blockIdx.x >> 3;
    const int nchunk   = blockIdx.x & 7;
    const int rowBase  = rowBlock * 128 + wave * 32;

    const uint4* A = (const uint4*)a_hat;     // row stride = 128*2/16 = 16 uint4

    // A fragments: [strip][kstep], lane holds A[m=l15][k = quad*8 .. +7] (+32*kstep)
    bf16x8 afrag[2][4];
    #pragma unroll
    for (int s = 0; s < 2; ++s) {
        int r = rowBase + s * 16 + l15;
        #pragma unroll
        for (int k = 0; k < 4; ++k) {
            uint4 v = A[r * 16 + k * 4 + quad];
            afrag[s][k] = __builtin_bit_cast(bf16x8, v);
        }
    }

    // row labels for this lane's C-fragment rows: row = rowBase + s*16 + quad*4 + e
    int rlab[2][4];
    #pragma unroll
    for (int s = 0; s < 2; ++s)
        #pragma unroll
        for (int e = 0; e < 4; ++e)
            rlab[s][e] = labels[rowBase + s * 16 + quad * 4 + e];

    float gmax[2][4];
    #pragma unroll
    for (int s = 0; s < 2; ++s)
        #pragma unroll
        for (int e = 0; e < 4; ++e)
            gmax[s][e] = -4.0f;

    const int colBase0 = nchunk * 1024;
    for (int cb = 0; cb < 32; ++cb) {
        const int C = colBase0 + cb * 32;

        bf16x8 bfrag[2][4];
        #pragma unroll
        for (int s = 0; s < 2; ++s) {
            int c = C + s * 16 + l15;
            #pragma unroll
            for (int k = 0; k < 4; ++k) {
                uint4 v = A[c * 16 + k * 4 + quad];
                bfrag[s][k] = __builtin_bit_cast(bf16x8, v);
            }
        }
        int clab0 = labels[C + l15];
        int clab1 = labels[C + 16 + l15];

        #pragma unroll
        for (int ms = 0; ms < 2; ++ms) {
            #pragma unroll
            for (int ns = 0; ns < 2; ++ns) {
                floatx4 acc = {0.f, 0.f, 0.f, 0.f};
                #pragma unroll
                for (int k = 0; k < 4; ++k)
                    acc = __builtin_amdgcn_mfma_f32_16x16x32_bf16(
                              afrag[ms][k], bfrag[ns][k], acc, 0, 0, 0);
                const int cl = ns ? clab1 : clab0;
                #pragma unroll
                for (int e = 0; e < 4; ++e) {
                    float v = (cl != rlab[ms][e]) ? acc[e] : -4.0f;
                    gmax[ms][e] = fmaxf(gmax[ms][e], v);
                }
            }
        }
    }

    // reduce over the 16 lanes of each quad (cols), then atomicMax per row
    #pragma unroll
    for (int s = 0; s < 2; ++s) {
        #pragma unroll
        for (int e = 0; e < 4; ++e) {
            float v = gmax[s][e];
            #pragma unroll
            for (int off = 1; off < 16; off <<= 1)
                v = fmaxf(v, __shfl_xor(v, off));
            if (l15 == 0) {
                int r = rowBase + s * 16 + quad * 4 + e;
                atomicMax(g_ws + r, __float_as_int(2.0f + v));  // keys > 0: int order ok
            }
        }
    }
}

// ---------- kernel 3: final loss + mean ----------
__global__ __launch_bounds__(256) void loss_kernel(
    const float* __restrict__ pos_ws, const int* __restrict__ g_ws,
    float* __restrict__ out)
{
    const int i = blockIdx.x * 256 + threadIdx.x;
    float g    = __int_as_float(g_ws[i]) - 2.0f;
    float neg  = fmaxf(2.0f - 2.0f * g, 0.0f);
    float loss = fmaxf(pos_ws[i] - neg + 0.5f, 0.0f);

    #pragma unroll
    for (int off = 32; off; off >>= 1)
        loss += __shfl_xor(loss, off);

    __shared__ float ws[4];
    if ((threadIdx.x & 63) == 0) ws[threadIdx.x >> 6] = loss;
    __syncthreads();
    if (threadIdx.x == 0) {
        float s = ws[0] + ws[1] + ws[2] + ws[3];
        atomicAdd(out, s * (1.0f / 8192.0f));
    }
}

extern "C" void kernel_launch(void* const* d_in, const int* in_sizes, int n_in,
                              void* d_out, int out_size, void* d_ws, size_t ws_size,
                              hipStream_t stream) {
    const float* anchor   = (const float*)d_in[0];
    const float* positive = (const float*)d_in[1];
    const int*   labels   = (const int*)d_in[2];
    float* out = (float*)d_out;

    char* ws = (char*)d_ws;
    unsigned short* a_hat  = (unsigned short*)ws;                       // 2 MiB
    float*          pos_ws = (float*)(ws + 2 * 1024 * 1024);            // 32 KiB
    int*            g_ws   = (int*)  (ws + 2 * 1024 * 1024 + 32 * 1024);// 32 KiB

    hipMemsetAsync(d_out, 0, sizeof(float), stream);
    normalize_kernel<<<NROWS / 4, 256, 0, stream>>>(anchor, positive, a_hat, pos_ws, g_ws);
    gram_kernel<<<512, 256, 0, stream>>>(a_hat, labels, g_ws);
    loss_kernel<<<NROWS / 256, 256, 0, stream>>>(pos_ws, g_ws, out);
}

// Round 2
// 88.261 us; speedup vs baseline: 1.4784x; 1.4784x over previous
//
#include <hip/hip_runtime.h>
#include <stdint.h>

#define NROWS 8192
#define DIM 128

typedef __bf16 bf16x8 __attribute__((ext_vector_type(8)));
typedef float floatx4 __attribute__((ext_vector_type(4)));

// ---------- helpers ----------
static __device__ __forceinline__ unsigned short f2bf(float f) {
    unsigned int u = __float_as_uint(f);
    unsigned int r = (u + 0x7FFFu + ((u >> 16) & 1u)) >> 16;   // RNE
    return (unsigned short)r;
}

// XOR swizzle on linear uint4 index g (tile stored as 32 cols x 16 uint4):
// c = g>>4, i = g&15  ->  slot = c*16 + (i ^ (c&7)).
// Breaks the 16-way bank-group conflict of the naive layout (all lanes of a
// ds_read_b128 would hit one 4-bank group); swizzled access is 2-way = free.
static __device__ __forceinline__ int swz(int g) {
    return (g & ~15) | ((g & 15) ^ ((g >> 4) & 7));
}

// ---------- kernel 1: normalize rows, emit bf16 a_hat + pos_dist + init max keys ----------
__global__ __launch_bounds__(256) void normalize_kernel(
    const float* __restrict__ anchor, const float* __restrict__ positive,
    unsigned short* __restrict__ a_hat, float* __restrict__ pos_ws,
    int* __restrict__ g_ws)
{
    const int wave = threadIdx.x >> 6;
    const int lane = threadIdx.x & 63;
    const int row  = blockIdx.x * 4 + wave;

    const float2* arow = (const float2*)(anchor   + row * DIM);
    const float2* prow = (const float2*)(positive + row * DIM);
    float2 a = arow[lane];
    float2 p = prow[lane];

    float sa  = a.x * a.x + a.y * a.y;
    float sp  = p.x * p.x + p.y * p.y;
    float sap = a.x * p.x + a.y * p.y;
    #pragma unroll
    for (int off = 32; off; off >>= 1) {
        sa  += __shfl_xor(sa,  off);
        sp  += __shfl_xor(sp,  off);
        sap += __shfl_xor(sap, off);
    }
    float na  = fmaxf(sqrtf(sa), 1e-12f);
    float npn = fmaxf(sqrtf(sp), 1e-12f);
    float inv = 1.0f / na;

    ushort2 pack;
    pack.x = f2bf(a.x * inv);
    pack.y = f2bf(a.y * inv);
    ((ushort2*)a_hat)[row * 64 + lane] = pack;

    if (lane == 0) {
        pos_ws[row] = 2.0f - 2.0f * sap / (na * npn);
        g_ws[row]   = 0x3F800000;   // key for g = -1  (key = 2+g = 1.0f)
    }
}

// ---------- kernel 2: fused gram row-max with label mask ----------
// grid = 1024: blockIdx>>4 = row block (128 rows), blockIdx&15 = 512-col chunk.
// B tiles (32 cols x 128 dim, 8 KB) staged in double-buffered swizzled LDS,
// shared by all 4 waves; register prefetch of next tile; 1 barrier/iter.
__global__ __launch_bounds__(256, 4) void gram_kernel(
    const unsigned short* __restrict__ a_hat, const int* __restrict__ labels,
    int* __restrict__ g_ws)
{
    const int tid  = threadIdx.x;
    const int lane = tid & 63;
    const int wave = tid >> 6;
    const int quad = lane >> 4;
    const int l15  = lane & 15;

    const int rowBlock = blockIdx.x >> 4;     // 0..63
    const int nchunk   = blockIdx.x & 15;     // 0..15
    const int rowBase  = rowBlock * 128 + wave * 32;

    const uint4* A = (const uint4*)a_hat;     // row stride = 16 uint4 (256 B)

    __shared__ uint4 smem[2][512];            // 2 x 8 KB

    // A fragments: lane holds A[m=l15][k = quad*8..+7] (+32 per kstep)
    bf16x8 afrag[2][4];
    #pragma unroll
    for (int s = 0; s < 2; ++s) {
        int r = rowBase + s * 16 + l15;
        #pragma unroll
        for (int k = 0; k < 4; ++k) {
            uint4 v = A[r * 16 + k * 4 + quad];
            afrag[s][k] = __builtin_bit_cast(bf16x8, v);
        }
    }

    // row labels for this lane's C-fragment rows: row = rowBase + s*16 + quad*4 + e
    int rlab[2][4];
    #pragma unroll
    for (int s = 0; s < 2; ++s)
        #pragma unroll
        for (int e = 0; e < 4; ++e)
            rlab[s][e] = labels[rowBase + s * 16 + quad * 4 + e];

    float gmax[2][4];
    #pragma unroll
    for (int s = 0; s < 2; ++s)
        #pragma unroll
        for (int e = 0; e < 4; ++e)
            gmax[s][e] = -4.0f;

    const int colBase = nchunk * 512;                 // 512 cols = 16 tiles of 32
    const uint4* Gp = A + colBase * 16;               // tile cb at Gp + cb*512

    // stage tile 0
    uint4 p0 = Gp[tid];
    uint4 p1 = Gp[tid + 256];
    smem[0][swz(tid)]       = p0;
    smem[0][swz(tid + 256)] = p1;
    __syncthreads();

    for (int cb = 0; cb < 16; ++cb) {
        const int cur = cb & 1;

        if (cb < 15) {                                // prefetch next tile
            p0 = Gp[(cb + 1) * 512 + tid];
            p1 = Gp[(cb + 1) * 512 + tid + 256];
        }

        const int C = colBase + cb * 32;
        int clab0 = labels[C + l15];
        int clab1 = labels[C + 16 + l15];

        bf16x8 bfrag[2][4];
        #pragma unroll
        for (int ns = 0; ns < 2; ++ns) {
            int c = ns * 16 + l15;
            #pragma unroll
            for (int k = 0; k < 4; ++k) {
                int g = c * 16 + k * 4 + quad;
                bfrag[ns][k] = __builtin_bit_cast(bf16x8, smem[cur][swz(g)]);
            }
        }

        #pragma unroll
        for (int ms = 0; ms < 2; ++ms) {
            #pragma unroll
            for (int ns = 0; ns < 2; ++ns) {
                floatx4 acc = {0.f, 0.f, 0.f, 0.f};
                #pragma unroll
                for (int k = 0; k < 4; ++k)
                    acc = __builtin_amdgcn_mfma_f32_16x16x32_bf16(
                              afrag[ms][k], bfrag[ns][k], acc, 0, 0, 0);
                const int cl = ns ? clab1 : clab0;
                #pragma unroll
                for (int e = 0; e < 4; ++e) {
                    float v = (cl != rlab[ms][e]) ? acc[e] : -4.0f;
                    gmax[ms][e] = fmaxf(gmax[ms][e], v);
                }
            }
        }

        if (cb < 15) {
            // write prefetched tile into the buffer NOT being read this iter.
            // Safe without a pre-write barrier: end-of-prev-iter barrier already
            // guarantees every wave finished reading that buffer.
            smem[cur ^ 1][swz(tid)]       = p0;
            smem[cur ^ 1][swz(tid + 256)] = p1;
            __syncthreads();
        }
    }

    // reduce over the 16 lanes of each quad (cols), then atomicMax per row
    #pragma unroll
    for (int s = 0; s < 2; ++s) {
        #pragma unroll
        for (int e = 0; e < 4; ++e) {
            float v = gmax[s][e];
            #pragma unroll
            for (int off = 1; off < 16; off <<= 1)
                v = fmaxf(v, __shfl_xor(v, off));
            if (l15 == 0) {
                int r = rowBase + s * 16 + quad * 4 + e;
                atomicMax(g_ws + r, __float_as_int(2.0f + v));  // keys > 0: int order ok
            }
        }
    }
}

// ---------- kernel 3: final loss + mean ----------
__global__ __launch_bounds__(256) void loss_kernel(
    const float* __restrict__ pos_ws, const int* __restrict__ g_ws,
    float* __restrict__ out)
{
    const int i = blockIdx.x * 256 + threadIdx.x;
    float g    = __int_as_float(g_ws[i]) - 2.0f;
    float neg  = fmaxf(2.0f - 2.0f * g, 0.0f);
    float loss = fmaxf(pos_ws[i] - neg + 0.5f, 0.0f);

    #pragma unroll
    for (int off = 32; off; off >>= 1)
        loss += __shfl_xor(loss, off);

    __shared__ float ws[4];
    if ((threadIdx.x & 63) == 0) ws[threadIdx.x >> 6] = loss;
    __syncthreads();
    if (threadIdx.x == 0) {
        float s = ws[0] + ws[1] + ws[2] + ws[3];
        atomicAdd(out, s * (1.0f / 8192.0f));
    }
}

extern "C" void kernel_launch(void* const* d_in, const int* in_sizes, int n_in,
                              void* d_out, int out_size, void* d_ws, size_t ws_size,
                              hipStream_t stream) {
    const float* anchor   = (const float*)d_in[0];
    const float* positive = (const float*)d_in[1];
    const int*   labels   = (const int*)d_in[2];
    float* out = (float*)d_out;

    char* ws = (char*)d_ws;
    unsigned short* a_hat  = (unsigned short*)ws;                       // 2 MiB
    float*          pos_ws = (float*)(ws + 2 * 1024 * 1024);            // 32 KiB
    int*            g_ws   = (int*)  (ws + 2 * 1024 * 1024 + 32 * 1024);// 32 KiB

    hipMemsetAsync(d_out, 0, sizeof(float), stream);
    normalize_kernel<<<NROWS / 4, 256, 0, stream>>>(anchor, positive, a_hat, pos_ws, g_ws);
    gram_kernel<<<1024, 256, 0, stream>>>(a_hat, labels, g_ws);
    loss_kernel<<<NROWS / 256, 256, 0, stream>>>(pos_ws, g_ws, out);
}